// Round 1
// baseline (2719.918 us; speedup 1.0000x reference)
//
#include <hip/hip_runtime.h>
#include <math.h>

#define NN 100000
#define DD 128
#define LEAKY 0.5f

// out[i] = 0 over n float4s
__global__ void zero4_kernel(float4* __restrict__ out, int n4) {
    int i = blockIdx.x * blockDim.x + threadIdx.x;
    int stride = gridDim.x * blockDim.x;
    float4 z = make_float4(0.f, 0.f, 0.f, 0.f);
    for (; i < n4; i += stride) out[i] = z;
}

// gated = embeds * (2*sigmoid(z) - 1), vectorized float4
__global__ void gate_kernel(const float4* __restrict__ emb,
                            const float4* __restrict__ zs,
                            float4* __restrict__ gated, int n4) {
    int i = blockIdx.x * blockDim.x + threadIdx.x;
    int stride = gridDim.x * blockDim.x;
    for (; i < n4; i += stride) {
        float4 e = emb[i];
        float4 z = zs[i];
        float4 g;
        g.x = e.x * (2.f / (1.f + __expf(-z.x)) - 1.f);
        g.y = e.y * (2.f / (1.f + __expf(-z.y)) - 1.f);
        g.z = e.z * (2.f / (1.f + __expf(-z.z)) - 1.f);
        g.w = e.w * (2.f / (1.f + __expf(-z.w)) - 1.f);
        gated[i] = g;
    }
}

// 32 threads per edge; each thread handles 4 contiguous d (float4 gather, 4 atomics)
__global__ void scatter_kernel(const int* __restrict__ row,
                               const int* __restrict__ col,
                               const float* __restrict__ val,
                               const float* __restrict__ gated,
                               float* __restrict__ out, int E) {
    int gid = blockIdx.x * blockDim.x + threadIdx.x;
    int e = gid >> 5;
    if (e >= E) return;
    int lane = gid & 31;
    int r = row[e];
    int c = col[e];
    float v = val[e];
    const float4* g = (const float4*)(gated + (size_t)c * DD);
    float4 gv = g[lane];
    float* o = out + (size_t)r * DD + lane * 4;
    atomicAdd(o + 0, v * gv.x);
    atomicAdd(o + 1, v * gv.y);
    atomicAdd(o + 2, v * gv.z);
    atomicAdd(o + 3, v * gv.w);
}

// fallback scatter when ws too small: compute gate on the fly
__global__ void scatter_fused_kernel(const int* __restrict__ row,
                                     const int* __restrict__ col,
                                     const float* __restrict__ val,
                                     const float* __restrict__ emb,
                                     const float* __restrict__ zs,
                                     float* __restrict__ out, int E) {
    int gid = blockIdx.x * blockDim.x + threadIdx.x;
    int e = gid >> 5;
    if (e >= E) return;
    int lane = gid & 31;
    int r = row[e];
    int c = col[e];
    float v = val[e];
    const float4* ep = (const float4*)(emb + (size_t)c * DD);
    const float4* zp = (const float4*)(zs + (size_t)c * DD);
    float4 ev = ep[lane];
    float4 zv = zp[lane];
    float4 gv;
    gv.x = ev.x * (2.f / (1.f + __expf(-zv.x)) - 1.f);
    gv.y = ev.y * (2.f / (1.f + __expf(-zv.y)) - 1.f);
    gv.z = ev.z * (2.f / (1.f + __expf(-zv.z)) - 1.f);
    gv.w = ev.w * (2.f / (1.f + __expf(-zv.w)) - 1.f);
    float* o = out + (size_t)r * DD + lane * 4;
    atomicAdd(o + 0, v * gv.x);
    atomicAdd(o + 1, v * gv.y);
    atomicAdd(o + 2, v * gv.z);
    atomicAdd(o + 3, v * gv.w);
}

// leaky relu in place
__global__ void leaky_kernel(float4* __restrict__ out, int n4) {
    int i = blockIdx.x * blockDim.x + threadIdx.x;
    int stride = gridDim.x * blockDim.x;
    for (; i < n4; i += stride) {
        float4 x = out[i];
        x.x = x.x > 0.f ? x.x : LEAKY * x.x;
        x.y = x.y > 0.f ? x.y : LEAKY * x.y;
        x.z = x.z > 0.f ? x.z : LEAKY * x.z;
        x.w = x.w > 0.f ? x.w : LEAKY * x.w;
        out[i] = x;
    }
}

extern "C" void kernel_launch(void* const* d_in, const int* in_sizes, int n_in,
                              void* d_out, int out_size, void* d_ws, size_t ws_size,
                              hipStream_t stream) {
    const int* row_idx = (const int*)d_in[0];
    const int* col_idx = (const int*)d_in[1];
    const float* adj_vals = (const float*)d_in[2];
    const float* embeds = (const float*)d_in[3];
    const float* zishiying = (const float*)d_in[4];
    float* out = (float*)d_out;

    const int E = in_sizes[0];
    const int ND = in_sizes[3];       // N_NODES * 128
    const int n4 = ND / 4;            // 3.2M float4

    // zero output (poisoned by harness)
    {
        int blocks = min((n4 + 255) / 256, 2048);
        hipLaunchKernelGGL(zero4_kernel, dim3(blocks), dim3(256), 0, stream,
                           (float4*)out, n4);
    }

    const size_t need = (size_t)ND * sizeof(float);
    const bool use_ws = ws_size >= need;

    if (use_ws) {
        float* gated = (float*)d_ws;
        int blocks = min((n4 + 255) / 256, 2048);
        hipLaunchKernelGGL(gate_kernel, dim3(blocks), dim3(256), 0, stream,
                           (const float4*)embeds, (const float4*)zishiying,
                           (float4*)gated, n4);
        long long total = (long long)E * 32;
        int sblocks = (int)((total + 255) / 256);
        hipLaunchKernelGGL(scatter_kernel, dim3(sblocks), dim3(256), 0, stream,
                           row_idx, col_idx, adj_vals, gated, out, E);
    } else {
        long long total = (long long)E * 32;
        int sblocks = (int)((total + 255) / 256);
        hipLaunchKernelGGL(scatter_fused_kernel, dim3(sblocks), dim3(256), 0, stream,
                           row_idx, col_idx, adj_vals, embeds, zishiying, out, E);
    }

    {
        int blocks = min((n4 + 255) / 256, 2048);
        hipLaunchKernelGGL(leaky_kernel, dim3(blocks), dim3(256), 0, stream,
                           (float4*)out, n4);
    }
}

// Round 2
// 428.050 us; speedup vs baseline: 6.3542x; 6.3542x over previous
//
#include <hip/hip_runtime.h>
#include <math.h>

#define DD 128
#define LEAKY 0.5f

// ---------------- shared helpers ----------------

__global__ void zero4_kernel(float4* __restrict__ out, int n4) {
    int i = blockIdx.x * blockDim.x + threadIdx.x;
    int stride = gridDim.x * blockDim.x;
    float4 z = make_float4(0.f, 0.f, 0.f, 0.f);
    for (; i < n4; i += stride) out[i] = z;
}

// gated = embeds * (2*sigmoid(z) - 1), vectorized float4
__global__ void gate_kernel(const float4* __restrict__ emb,
                            const float4* __restrict__ zs,
                            float4* __restrict__ gated, int n4) {
    int i = blockIdx.x * blockDim.x + threadIdx.x;
    int stride = gridDim.x * blockDim.x;
    for (; i < n4; i += stride) {
        float4 e = emb[i];
        float4 z = zs[i];
        float4 g;
        g.x = e.x * (2.f / (1.f + __expf(-z.x)) - 1.f);
        g.y = e.y * (2.f / (1.f + __expf(-z.y)) - 1.f);
        g.z = e.z * (2.f / (1.f + __expf(-z.z)) - 1.f);
        g.w = e.w * (2.f / (1.f + __expf(-z.w)) - 1.f);
        gated[i] = g;
    }
}

// ---------------- CSR build ----------------

__global__ void count_kernel(const int* __restrict__ row, int* __restrict__ counts, int E) {
    int i = blockIdx.x * blockDim.x + threadIdx.x;
    int stride = gridDim.x * blockDim.x;
    for (; i < E; i += stride) atomicAdd(&counts[row[i]], 1);
}

// single-workgroup exclusive scan over n ints (1024 threads = 16 waves)
__global__ void scan_kernel(const int* __restrict__ counts,
                            int* __restrict__ starts,
                            int* __restrict__ cursor, int n) {
    __shared__ int wsum[16];
    __shared__ int wpre[16];
    __shared__ int total_s;
    __shared__ int carry;
    const int tid = threadIdx.x;
    const int lane = tid & 63;
    const int wid = tid >> 6;
    if (tid == 0) carry = 0;
    __syncthreads();
    for (int base = 0; base < n; base += 1024) {
        int i = base + tid;
        int v = (i < n) ? counts[i] : 0;
        // wave inclusive scan
        int x = v;
        #pragma unroll
        for (int off = 1; off < 64; off <<= 1) {
            int t = __shfl_up(x, off, 64);
            if (lane >= off) x += t;
        }
        if (lane == 63) wsum[wid] = x;
        __syncthreads();
        if (tid < 16) {
            int s = wsum[tid];
            #pragma unroll
            for (int off = 1; off < 16; off <<= 1) {
                int t = __shfl_up(s, off, 64);
                if (tid >= off) s += t;
            }
            wpre[tid] = s - wsum[tid];
            if (tid == 15) total_s = s;
        }
        __syncthreads();
        int basev = carry;
        int excl = basev + wpre[wid] + (x - v);
        if (i < n) { starts[i] = excl; cursor[i] = excl; }
        __syncthreads();
        if (tid == 0) carry += total_s;
        __syncthreads();
    }
    if (tid == 0) starts[n] = carry;
}

// scatter edge (col,val) into CSR slots grouped by destination row
__global__ void fill_kernel(const int* __restrict__ row, const int* __restrict__ col,
                            const float* __restrict__ val, int* __restrict__ cursor,
                            int2* __restrict__ csr, int E) {
    int i = blockIdx.x * blockDim.x + threadIdx.x;
    int stride = gridDim.x * blockDim.x;
    for (; i < E; i += stride) {
        int r = row[i];
        int slot = atomicAdd(&cursor[r], 1);
        csr[slot] = make_int2(col[i], __float_as_int(val[i]));
    }
}

// one wave per destination row; lane owns float2 of D; fused leaky-relu write
__global__ void gather_kernel(const int* __restrict__ starts,
                              const int2* __restrict__ csr,
                              const float* __restrict__ gated,
                              float* __restrict__ out, int N) {
    int gid = blockIdx.x * blockDim.x + threadIdx.x;
    int r = gid >> 6;
    if (r >= N) return;
    int lane = gid & 63;
    int beg = starts[r];
    int end = starts[r + 1];
    const float2* gbase = (const float2*)gated;
    float2 acc = make_float2(0.f, 0.f);
    int j = beg;
    for (; j + 1 < end; j += 2) {
        int2 cv0 = csr[j];
        int2 cv1 = csr[j + 1];
        float2 g0 = gbase[(size_t)cv0.x * 64 + lane];
        float2 g1 = gbase[(size_t)cv1.x * 64 + lane];
        float v0 = __int_as_float(cv0.y);
        float v1 = __int_as_float(cv1.y);
        acc.x += v0 * g0.x;
        acc.y += v0 * g0.y;
        acc.x += v1 * g1.x;
        acc.y += v1 * g1.y;
    }
    if (j < end) {
        int2 cv = csr[j];
        float2 g = gbase[(size_t)cv.x * 64 + lane];
        float v = __int_as_float(cv.y);
        acc.x += v * g.x;
        acc.y += v * g.y;
    }
    acc.x = acc.x > 0.f ? acc.x : LEAKY * acc.x;
    acc.y = acc.y > 0.f ? acc.y : LEAKY * acc.y;
    ((float2*)out)[(size_t)r * 64 + lane] = acc;
}

// ---------------- fallback atomic path (round-1, known-good) ----------------

__global__ void scatter_kernel(const int* __restrict__ row,
                               const int* __restrict__ col,
                               const float* __restrict__ val,
                               const float* __restrict__ gated,
                               float* __restrict__ out, int E) {
    int gid = blockIdx.x * blockDim.x + threadIdx.x;
    int e = gid >> 5;
    if (e >= E) return;
    int lane = gid & 31;
    int r = row[e];
    int c = col[e];
    float v = val[e];
    const float4* g = (const float4*)(gated + (size_t)c * DD);
    float4 gv = g[lane];
    float* o = out + (size_t)r * DD + lane * 4;
    atomicAdd(o + 0, v * gv.x);
    atomicAdd(o + 1, v * gv.y);
    atomicAdd(o + 2, v * gv.z);
    atomicAdd(o + 3, v * gv.w);
}

__global__ void scatter_fused_kernel(const int* __restrict__ row,
                                     const int* __restrict__ col,
                                     const float* __restrict__ val,
                                     const float* __restrict__ emb,
                                     const float* __restrict__ zs,
                                     float* __restrict__ out, int E) {
    int gid = blockIdx.x * blockDim.x + threadIdx.x;
    int e = gid >> 5;
    if (e >= E) return;
    int lane = gid & 31;
    int r = row[e];
    int c = col[e];
    float v = val[e];
    const float4* ep = (const float4*)(emb + (size_t)c * DD);
    const float4* zp = (const float4*)(zs + (size_t)c * DD);
    float4 ev = ep[lane];
    float4 zv = zp[lane];
    float4 gv;
    gv.x = ev.x * (2.f / (1.f + __expf(-zv.x)) - 1.f);
    gv.y = ev.y * (2.f / (1.f + __expf(-zv.y)) - 1.f);
    gv.z = ev.z * (2.f / (1.f + __expf(-zv.z)) - 1.f);
    gv.w = ev.w * (2.f / (1.f + __expf(-zv.w)) - 1.f);
    float* o = out + (size_t)r * DD + lane * 4;
    atomicAdd(o + 0, v * gv.x);
    atomicAdd(o + 1, v * gv.y);
    atomicAdd(o + 2, v * gv.z);
    atomicAdd(o + 3, v * gv.w);
}

__global__ void leaky_kernel(float4* __restrict__ out, int n4) {
    int i = blockIdx.x * blockDim.x + threadIdx.x;
    int stride = gridDim.x * blockDim.x;
    for (; i < n4; i += stride) {
        float4 x = out[i];
        x.x = x.x > 0.f ? x.x : LEAKY * x.x;
        x.y = x.y > 0.f ? x.y : LEAKY * x.y;
        x.z = x.z > 0.f ? x.z : LEAKY * x.z;
        x.w = x.w > 0.f ? x.w : LEAKY * x.w;
        out[i] = x;
    }
}

// ---------------- launch ----------------

extern "C" void kernel_launch(void* const* d_in, const int* in_sizes, int n_in,
                              void* d_out, int out_size, void* d_ws, size_t ws_size,
                              hipStream_t stream) {
    const int* row_idx = (const int*)d_in[0];
    const int* col_idx = (const int*)d_in[1];
    const float* adj_vals = (const float*)d_in[2];
    const float* embeds = (const float*)d_in[3];
    const float* zishiying = (const float*)d_in[4];
    float* out = (float*)d_out;

    const int E = in_sizes[0];
    const int ND = in_sizes[3];       // N * 128
    const int N = ND / DD;
    const int n4 = ND / 4;

    // ws layout
    char* p = (char*)d_ws;
    float* gated = (float*)p;               p += (size_t)ND * 4;
    int* counts = (int*)p;                  p += (size_t)N * 4;
    int* starts = (int*)p;                  p += (size_t)(N + 1) * 4;
    int* cursor = (int*)p;                  p += (size_t)N * 4;
    p = (char*)(((uintptr_t)p + 7) & ~(uintptr_t)7);
    int2* csr = (int2*)p;                   p += (size_t)E * 8;
    const size_t need_csr = (size_t)(p - (char*)d_ws);
    const size_t need_gated = (size_t)ND * 4;

    if (ws_size >= need_csr) {
        // 1. gate
        {
            int blocks = min((n4 + 255) / 256, 2048);
            hipLaunchKernelGGL(gate_kernel, dim3(blocks), dim3(256), 0, stream,
                               (const float4*)embeds, (const float4*)zishiying,
                               (float4*)gated, n4);
        }
        // 2. zero counts
        hipMemsetAsync(counts, 0, (size_t)N * 4, stream);
        // 3. count
        {
            int blocks = min((E + 255) / 256, 2048);
            hipLaunchKernelGGL(count_kernel, dim3(blocks), dim3(256), 0, stream,
                               row_idx, counts, E);
        }
        // 4. scan (single block)
        hipLaunchKernelGGL(scan_kernel, dim3(1), dim3(1024), 0, stream,
                           counts, starts, cursor, N);
        // 5. fill CSR
        {
            int blocks = min((E + 255) / 256, 2048);
            hipLaunchKernelGGL(fill_kernel, dim3(blocks), dim3(256), 0, stream,
                               row_idx, col_idx, adj_vals, cursor, csr, E);
        }
        // 6. gather + leaky (writes every output element exactly once)
        {
            long long total = (long long)N * 64;
            int blocks = (int)((total + 255) / 256);
            hipLaunchKernelGGL(gather_kernel, dim3(blocks), dim3(256), 0, stream,
                               starts, csr, gated, out, N);
        }
        return;
    }

    // ---------- fallback: round-1 atomic path ----------
    {
        int blocks = min((n4 + 255) / 256, 2048);
        hipLaunchKernelGGL(zero4_kernel, dim3(blocks), dim3(256), 0, stream,
                           (float4*)out, n4);
    }
    if (ws_size >= need_gated) {
        int blocks = min((n4 + 255) / 256, 2048);
        hipLaunchKernelGGL(gate_kernel, dim3(blocks), dim3(256), 0, stream,
                           (const float4*)embeds, (const float4*)zishiying,
                           (float4*)gated, n4);
        long long total = (long long)E * 32;
        int sblocks = (int)((total + 255) / 256);
        hipLaunchKernelGGL(scatter_kernel, dim3(sblocks), dim3(256), 0, stream,
                           row_idx, col_idx, adj_vals, gated, out, E);
    } else {
        long long total = (long long)E * 32;
        int sblocks = (int)((total + 255) / 256);
        hipLaunchKernelGGL(scatter_fused_kernel, dim3(sblocks), dim3(256), 0, stream,
                           row_idx, col_idx, adj_vals, embeds, zishiying, out, E);
    }
    {
        int blocks = min((n4 + 255) / 256, 2048);
        hipLaunchKernelGGL(leaky_kernel, dim3(blocks), dim3(256), 0, stream,
                           (float4*)out, n4);
    }
}

// Round 3
// 276.176 us; speedup vs baseline: 9.8485x; 1.5499x over previous
//
#include <hip/hip_runtime.h>
#include <math.h>

#define DD 128
#define LEAKY 0.5f

// ---------------- shared helpers ----------------

__global__ void zero4_kernel(float4* __restrict__ out, int n4) {
    int i = blockIdx.x * blockDim.x + threadIdx.x;
    int stride = gridDim.x * blockDim.x;
    float4 z = make_float4(0.f, 0.f, 0.f, 0.f);
    for (; i < n4; i += stride) out[i] = z;
}

// gated = embeds * (2*sigmoid(z) - 1), vectorized float4
__global__ void gate_kernel(const float4* __restrict__ emb,
                            const float4* __restrict__ zs,
                            float4* __restrict__ gated, int n4) {
    int i = blockIdx.x * blockDim.x + threadIdx.x;
    int stride = gridDim.x * blockDim.x;
    for (; i < n4; i += stride) {
        float4 e = emb[i];
        float4 z = zs[i];
        float4 g;
        g.x = e.x * (2.f / (1.f + __expf(-z.x)) - 1.f);
        g.y = e.y * (2.f / (1.f + __expf(-z.y)) - 1.f);
        g.z = e.z * (2.f / (1.f + __expf(-z.z)) - 1.f);
        g.w = e.w * (2.f / (1.f + __expf(-z.w)) - 1.f);
        gated[i] = g;
    }
}

// ---------------- CSR build ----------------

// counts[r]++ AND record each edge's rank within its row (atomic return is free)
__global__ void rank_kernel(const int* __restrict__ row, int* __restrict__ counts,
                            int* __restrict__ rank, int E) {
    int i = blockIdx.x * blockDim.x + threadIdx.x;
    if (i >= E) return;
    rank[i] = atomicAdd(&counts[row[i]], 1);
}

// single-workgroup exclusive scan, int4: 4096 elements per iteration
__global__ void scan_kernel(const int* __restrict__ counts,
                            int* __restrict__ starts, int n) {
    __shared__ int wsum[16];
    __shared__ int wpre[16];
    __shared__ int total_s;
    __shared__ int carry_s;
    const int tid = threadIdx.x;
    const int lane = tid & 63;
    const int wid = tid >> 6;
    if (tid == 0) carry_s = 0;
    __syncthreads();
    const int4* c4 = (const int4*)counts;
    for (int base = 0; base < n; base += 4096) {
        int i0 = base + tid * 4;
        int4 v = make_int4(0, 0, 0, 0);
        if (i0 + 3 < n) {
            v = c4[i0 >> 2];
        } else {
            if (i0 + 0 < n) v.x = counts[i0 + 0];
            if (i0 + 1 < n) v.y = counts[i0 + 1];
            if (i0 + 2 < n) v.z = counts[i0 + 2];
            if (i0 + 3 < n) v.w = counts[i0 + 3];
        }
        int s0 = v.x, s1 = s0 + v.y, s2 = s1 + v.z, s3 = s2 + v.w;
        int x = s3;
        #pragma unroll
        for (int off = 1; off < 64; off <<= 1) {
            int t = __shfl_up(x, off, 64);
            if (lane >= off) x += t;
        }
        if (lane == 63) wsum[wid] = x;
        __syncthreads();
        if (tid < 16) {
            int s = wsum[tid];
            #pragma unroll
            for (int off = 1; off < 16; off <<= 1) {
                int t = __shfl_up(s, off, 64);
                if (tid >= off) s += t;
            }
            wpre[tid] = s - wsum[tid];
            if (tid == 15) total_s = s;
        }
        __syncthreads();
        int pre = carry_s + wpre[wid] + (x - s3);
        int4 o;
        o.x = pre;
        o.y = pre + s0;
        o.z = pre + s1;
        o.w = pre + s2;
        if (i0 + 3 < n) {
            ((int4*)starts)[i0 >> 2] = o;
        } else {
            if (i0 + 0 < n) starts[i0 + 0] = o.x;
            if (i0 + 1 < n) starts[i0 + 1] = o.y;
            if (i0 + 2 < n) starts[i0 + 2] = o.z;
            if (i0 + 3 < n) starts[i0 + 3] = o.w;
        }
        __syncthreads();
        if (tid == 0) carry_s += total_s;
        __syncthreads();
    }
    if (tid == 0) starts[n] = carry_s;
}

// atomic-free fill: slot = starts[row] + rank
__global__ void fill_rank_kernel(const int* __restrict__ row, const int* __restrict__ col,
                                 const float* __restrict__ val,
                                 const int* __restrict__ rank,
                                 const int* __restrict__ starts,
                                 int2* __restrict__ csr, int E) {
    int i = blockIdx.x * blockDim.x + threadIdx.x;
    if (i >= E) return;
    int r = row[i];
    int slot = starts[r] + rank[i];
    csr[slot] = make_int2(col[i], __float_as_int(val[i]));
}

// one wave per destination row; lane owns float2 of D; fused leaky-relu write
__global__ void gather_kernel(const int* __restrict__ starts,
                              const int2* __restrict__ csr,
                              const float* __restrict__ gated,
                              float* __restrict__ out, int N) {
    int gid = blockIdx.x * blockDim.x + threadIdx.x;
    int r = gid >> 6;
    if (r >= N) return;
    int lane = gid & 63;
    int beg = __builtin_amdgcn_readfirstlane(starts[r]);
    int end = __builtin_amdgcn_readfirstlane(starts[r + 1]);
    const float2* gbase = (const float2*)gated;
    float2 acc = make_float2(0.f, 0.f);
    int j = beg;
    for (; j + 1 < end; j += 2) {
        int2 cv0 = csr[j];
        int2 cv1 = csr[j + 1];
        float2 g0 = gbase[(size_t)cv0.x * 64 + lane];
        float2 g1 = gbase[(size_t)cv1.x * 64 + lane];
        float v0 = __int_as_float(cv0.y);
        float v1 = __int_as_float(cv1.y);
        acc.x += v0 * g0.x;
        acc.y += v0 * g0.y;
        acc.x += v1 * g1.x;
        acc.y += v1 * g1.y;
    }
    if (j < end) {
        int2 cv = csr[j];
        float2 g = gbase[(size_t)cv.x * 64 + lane];
        float v = __int_as_float(cv.y);
        acc.x += v * g.x;
        acc.y += v * g.y;
    }
    acc.x = acc.x > 0.f ? acc.x : LEAKY * acc.x;
    acc.y = acc.y > 0.f ? acc.y : LEAKY * acc.y;
    ((float2*)out)[(size_t)r * 64 + lane] = acc;
}

// ---------------- fallback kernels (round-1/2, known-good) ----------------

__global__ void fill_kernel(const int* __restrict__ row, const int* __restrict__ col,
                            const float* __restrict__ val, int* __restrict__ cursor,
                            int2* __restrict__ csr, int E) {
    int i = blockIdx.x * blockDim.x + threadIdx.x;
    int stride = gridDim.x * blockDim.x;
    for (; i < E; i += stride) {
        int r = row[i];
        int slot = atomicAdd(&cursor[r], 1);
        csr[slot] = make_int2(col[i], __float_as_int(val[i]));
    }
}

__global__ void count_kernel(const int* __restrict__ row, int* __restrict__ counts, int E) {
    int i = blockIdx.x * blockDim.x + threadIdx.x;
    int stride = gridDim.x * blockDim.x;
    for (; i < E; i += stride) atomicAdd(&counts[row[i]], 1);
}

__global__ void copy_int_kernel(const int* __restrict__ src, int* __restrict__ dst, int n) {
    int i = blockIdx.x * blockDim.x + threadIdx.x;
    int stride = gridDim.x * blockDim.x;
    for (; i < n; i += stride) dst[i] = src[i];
}

__global__ void scatter_fused_kernel(const int* __restrict__ row,
                                     const int* __restrict__ col,
                                     const float* __restrict__ val,
                                     const float* __restrict__ emb,
                                     const float* __restrict__ zs,
                                     float* __restrict__ out, int E) {
    int gid = blockIdx.x * blockDim.x + threadIdx.x;
    int e = gid >> 5;
    if (e >= E) return;
    int lane = gid & 31;
    int r = row[e];
    int c = col[e];
    float v = val[e];
    const float4* ep = (const float4*)(emb + (size_t)c * DD);
    const float4* zp = (const float4*)(zs + (size_t)c * DD);
    float4 ev = ep[lane];
    float4 zv = zp[lane];
    float4 gv;
    gv.x = ev.x * (2.f / (1.f + __expf(-zv.x)) - 1.f);
    gv.y = ev.y * (2.f / (1.f + __expf(-zv.y)) - 1.f);
    gv.z = ev.z * (2.f / (1.f + __expf(-zv.z)) - 1.f);
    gv.w = ev.w * (2.f / (1.f + __expf(-zv.w)) - 1.f);
    float* o = out + (size_t)r * DD + lane * 4;
    atomicAdd(o + 0, v * gv.x);
    atomicAdd(o + 1, v * gv.y);
    atomicAdd(o + 2, v * gv.z);
    atomicAdd(o + 3, v * gv.w);
}

__global__ void leaky_kernel(float4* __restrict__ out, int n4) {
    int i = blockIdx.x * blockDim.x + threadIdx.x;
    int stride = gridDim.x * blockDim.x;
    for (; i < n4; i += stride) {
        float4 x = out[i];
        x.x = x.x > 0.f ? x.x : LEAKY * x.x;
        x.y = x.y > 0.f ? x.y : LEAKY * x.y;
        x.z = x.z > 0.f ? x.z : LEAKY * x.z;
        x.w = x.w > 0.f ? x.w : LEAKY * x.w;
        out[i] = x;
    }
}

// ---------------- launch ----------------

extern "C" void kernel_launch(void* const* d_in, const int* in_sizes, int n_in,
                              void* d_out, int out_size, void* d_ws, size_t ws_size,
                              hipStream_t stream) {
    const int* row_idx = (const int*)d_in[0];
    const int* col_idx = (const int*)d_in[1];
    const float* adj_vals = (const float*)d_in[2];
    const float* embeds = (const float*)d_in[3];
    const float* zishiying = (const float*)d_in[4];
    float* out = (float*)d_out;

    const int E = in_sizes[0];
    const int ND = in_sizes[3];       // N * 128
    const int N = ND / DD;
    const int n4 = ND / 4;

    // ws layout
    char* p = (char*)d_ws;
    float* gated = (float*)p;               p += (size_t)ND * 4;
    int* counts = (int*)p;                  p += (size_t)N * 4;
    int* starts = (int*)p;                  p += (size_t)(N + 1) * 4;
    p = (char*)(((uintptr_t)p + 15) & ~(uintptr_t)15);
    int2* csr = (int2*)p;                   p += (size_t)E * 8;
    const size_t need_base = (size_t)(p - (char*)d_ws);
    int* rank = (int*)p;                    p += (size_t)E * 4;   // also used as cursor in fallback
    const size_t need_rank = (size_t)(p - (char*)d_ws);
    const size_t need_gated = (size_t)ND * 4;

    const int eb = (E + 255) / 256;       // one thread per edge
    const int gb = min((n4 + 255) / 256, 2048);

    if (ws_size >= need_rank) {
        hipLaunchKernelGGL(gate_kernel, dim3(gb), dim3(256), 0, stream,
                           (const float4*)embeds, (const float4*)zishiying,
                           (float4*)gated, n4);
        hipMemsetAsync(counts, 0, (size_t)N * 4, stream);
        hipLaunchKernelGGL(rank_kernel, dim3(eb), dim3(256), 0, stream,
                           row_idx, counts, rank, E);
        hipLaunchKernelGGL(scan_kernel, dim3(1), dim3(1024), 0, stream,
                           counts, starts, N);
        hipLaunchKernelGGL(fill_rank_kernel, dim3(eb), dim3(256), 0, stream,
                           row_idx, col_idx, adj_vals, rank, starts, csr, E);
        long long total = (long long)N * 64;
        int blocks = (int)((total + 255) / 256);
        hipLaunchKernelGGL(gather_kernel, dim3(blocks), dim3(256), 0, stream,
                           starts, csr, gated, out, N);
        return;
    }

    if (ws_size >= need_base) {
        // cursor-based CSR build (round-2 path); reuse counts as cursor via copy
        hipLaunchKernelGGL(gate_kernel, dim3(gb), dim3(256), 0, stream,
                           (const float4*)embeds, (const float4*)zishiying,
                           (float4*)gated, n4);
        hipMemsetAsync(counts, 0, (size_t)N * 4, stream);
        hipLaunchKernelGGL(count_kernel, dim3(min(eb, 2048)), dim3(256), 0, stream,
                           row_idx, counts, E);
        hipLaunchKernelGGL(scan_kernel, dim3(1), dim3(1024), 0, stream,
                           counts, starts, N);
        // reuse counts as cursor
        hipLaunchKernelGGL(copy_int_kernel, dim3(min((N + 255) / 256, 2048)), dim3(256), 0, stream,
                           starts, counts, N);
        hipLaunchKernelGGL(fill_kernel, dim3(min(eb, 2048)), dim3(256), 0, stream,
                           row_idx, col_idx, adj_vals, counts, csr, E);
        long long total = (long long)N * 64;
        int blocks = (int)((total + 255) / 256);
        hipLaunchKernelGGL(gather_kernel, dim3(blocks), dim3(256), 0, stream,
                           starts, csr, gated, out, N);
        return;
    }

    // ---------- last-resort atomic path ----------
    hipLaunchKernelGGL(zero4_kernel, dim3(gb), dim3(256), 0, stream, (float4*)out, n4);
    {
        long long total = (long long)E * 32;
        int sblocks = (int)((total + 255) / 256);
        hipLaunchKernelGGL(scatter_fused_kernel, dim3(sblocks), dim3(256), 0, stream,
                           row_idx, col_idx, adj_vals, embeds, zishiying, out, E);
    }
    hipLaunchKernelGGL(leaky_kernel, dim3(gb), dim3(256), 0, stream, (float4*)out, n4);
}

// Round 4
// 184.037 us; speedup vs baseline: 14.7792x; 1.5007x over previous
//
#include <hip/hip_runtime.h>
#include <hip/hip_fp16.h>
#include <math.h>

#define DD 128
#define LEAKY 0.5f
#define SCAN_CHUNK 512

// ---------------- gate ----------------

// fp32 gate (fallback path)
__global__ void gate_kernel(const float4* __restrict__ emb,
                            const float4* __restrict__ zs,
                            float4* __restrict__ gated, int n4) {
    int i = blockIdx.x * blockDim.x + threadIdx.x;
    int stride = gridDim.x * blockDim.x;
    for (; i < n4; i += stride) {
        float4 e = emb[i];
        float4 z = zs[i];
        float4 g;
        g.x = e.x * (2.f / (1.f + __expf(-z.x)) - 1.f);
        g.y = e.y * (2.f / (1.f + __expf(-z.y)) - 1.f);
        g.z = e.z * (2.f / (1.f + __expf(-z.z)) - 1.f);
        g.w = e.w * (2.f / (1.f + __expf(-z.w)) - 1.f);
        gated[i] = g;
    }
}

// fp16 gate: 8 floats in -> 8 halves out (16B store) per thread-iter
__global__ void gate_h_kernel(const float4* __restrict__ emb,
                              const float4* __restrict__ zs,
                              float4* __restrict__ gated_h, int n8) {
    int i = blockIdx.x * blockDim.x + threadIdx.x;
    int stride = gridDim.x * blockDim.x;
    for (; i < n8; i += stride) {
        float4 e0 = emb[2 * i], e1 = emb[2 * i + 1];
        float4 z0 = zs[2 * i], z1 = zs[2 * i + 1];
        float g0 = e0.x * (2.f / (1.f + __expf(-z0.x)) - 1.f);
        float g1 = e0.y * (2.f / (1.f + __expf(-z0.y)) - 1.f);
        float g2 = e0.z * (2.f / (1.f + __expf(-z0.z)) - 1.f);
        float g3 = e0.w * (2.f / (1.f + __expf(-z0.w)) - 1.f);
        float g4 = e1.x * (2.f / (1.f + __expf(-z1.x)) - 1.f);
        float g5 = e1.y * (2.f / (1.f + __expf(-z1.y)) - 1.f);
        float g6 = e1.z * (2.f / (1.f + __expf(-z1.z)) - 1.f);
        float g7 = e1.w * (2.f / (1.f + __expf(-z1.w)) - 1.f);
        union { __half2 h[4]; float4 f; } u;
        u.h[0] = __floats2half2_rn(g0, g1);
        u.h[1] = __floats2half2_rn(g2, g3);
        u.h[2] = __floats2half2_rn(g4, g5);
        u.h[3] = __floats2half2_rn(g6, g7);
        gated_h[i] = u.f;
    }
}

// ---------------- CSR build ----------------

__global__ void rank_kernel(const int* __restrict__ row, int* __restrict__ counts,
                            int* __restrict__ rank, int E) {
    int i = blockIdx.x * blockDim.x + threadIdx.x;
    if (i >= E) return;
    rank[i] = atomicAdd(&counts[row[i]], 1);
}

// --- multi-block scan: reduce -> scan partials -> apply ---

__global__ void scan_reduce_kernel(const int* __restrict__ counts,
                                   int* __restrict__ partials, int n) {
    int b = blockIdx.x;
    int base = b * SCAN_CHUNK;
    int tid = threadIdx.x;          // 256
    int v = 0;
    int i0 = base + tid;
    int i1 = base + 256 + tid;
    if (i0 < n) v = counts[i0];
    if (i1 < n) v += counts[i1];
    #pragma unroll
    for (int off = 32; off >= 1; off >>= 1) v += __shfl_down(v, off, 64);
    __shared__ int ws[4];
    int lane = tid & 63, wid = tid >> 6;
    if (lane == 0) ws[wid] = v;
    __syncthreads();
    if (tid == 0) partials[b] = ws[0] + ws[1] + ws[2] + ws[3];
}

// single block, nb <= 256: exclusive scan of partials in place; also starts[n]=E
__global__ void scan_partials_kernel(int* __restrict__ partials, int nb,
                                     int* __restrict__ starts, int n, int E) {
    int tid = threadIdx.x;
    int lane = tid & 63, wid = tid >> 6;
    int v = (tid < nb) ? partials[tid] : 0;
    int x = v;
    #pragma unroll
    for (int off = 1; off < 64; off <<= 1) {
        int t = __shfl_up(x, off, 64);
        if (lane >= off) x += t;
    }
    __shared__ int wsum[4];
    if (lane == 63) wsum[wid] = x;
    __syncthreads();
    int woff = 0;
    for (int w = 0; w < wid; ++w) woff += wsum[w];
    if (tid < nb) partials[tid] = woff + x - v;
    if (tid == 0) starts[n] = E;
}

// per-block exclusive scan of its 512-chunk, offset by partials[b]
__global__ void scan_apply_kernel(const int* __restrict__ counts,
                                  const int* __restrict__ partials,
                                  int* __restrict__ starts, int n) {
    int b = blockIdx.x;
    int base = b * SCAN_CHUNK;
    int tid = threadIdx.x;
    int i = base + 2 * tid;
    int v0 = (i < n) ? counts[i] : 0;
    int v1 = (i + 1 < n) ? counts[i + 1] : 0;
    int s = v0 + v1;
    int lane = tid & 63, wid = tid >> 6;
    int x = s;
    #pragma unroll
    for (int off = 1; off < 64; off <<= 1) {
        int t = __shfl_up(x, off, 64);
        if (lane >= off) x += t;
    }
    __shared__ int wsum[4];
    if (lane == 63) wsum[wid] = x;
    __syncthreads();
    int woff = 0;
    for (int w = 0; w < wid; ++w) woff += wsum[w];
    int excl = partials[b] + woff + (x - s);
    if (i < n) starts[i] = excl;
    if (i + 1 < n) starts[i + 1] = excl + v0;
}

// legacy single-block scan (fallback when nb > 256)
__global__ void scan_kernel(const int* __restrict__ counts,
                            int* __restrict__ starts, int n) {
    __shared__ int wsum[16];
    __shared__ int wpre[16];
    __shared__ int total_s;
    __shared__ int carry_s;
    const int tid = threadIdx.x;
    const int lane = tid & 63;
    const int wid = tid >> 6;
    if (tid == 0) carry_s = 0;
    __syncthreads();
    const int4* c4 = (const int4*)counts;
    for (int base = 0; base < n; base += 4096) {
        int i0 = base + tid * 4;
        int4 v = make_int4(0, 0, 0, 0);
        if (i0 + 3 < n) {
            v = c4[i0 >> 2];
        } else {
            if (i0 + 0 < n) v.x = counts[i0 + 0];
            if (i0 + 1 < n) v.y = counts[i0 + 1];
            if (i0 + 2 < n) v.z = counts[i0 + 2];
            if (i0 + 3 < n) v.w = counts[i0 + 3];
        }
        int s0 = v.x, s1 = s0 + v.y, s2 = s1 + v.z, s3 = s2 + v.w;
        int x = s3;
        #pragma unroll
        for (int off = 1; off < 64; off <<= 1) {
            int t = __shfl_up(x, off, 64);
            if (lane >= off) x += t;
        }
        if (lane == 63) wsum[wid] = x;
        __syncthreads();
        if (tid < 16) {
            int s = wsum[tid];
            #pragma unroll
            for (int off = 1; off < 16; off <<= 1) {
                int t = __shfl_up(s, off, 64);
                if (tid >= off) s += t;
            }
            wpre[tid] = s - wsum[tid];
            if (tid == 15) total_s = s;
        }
        __syncthreads();
        int pre = carry_s + wpre[wid] + (x - s3);
        int4 o;
        o.x = pre; o.y = pre + s0; o.z = pre + s1; o.w = pre + s2;
        if (i0 + 3 < n) {
            ((int4*)starts)[i0 >> 2] = o;
        } else {
            if (i0 + 0 < n) starts[i0 + 0] = o.x;
            if (i0 + 1 < n) starts[i0 + 1] = o.y;
            if (i0 + 2 < n) starts[i0 + 2] = o.z;
            if (i0 + 3 < n) starts[i0 + 3] = o.w;
        }
        __syncthreads();
        if (tid == 0) carry_s += total_s;
        __syncthreads();
    }
    if (tid == 0) starts[n] = carry_s;
}

// atomic-free fill: slot = starts[row] + rank
__global__ void fill_rank_kernel(const int* __restrict__ row, const int* __restrict__ col,
                                 const float* __restrict__ val,
                                 const int* __restrict__ rank,
                                 const int* __restrict__ starts,
                                 int2* __restrict__ csr, int E) {
    int i = blockIdx.x * blockDim.x + threadIdx.x;
    if (i >= E) return;
    int r = row[i];
    int slot = starts[r] + rank[i];
    csr[slot] = make_int2(col[i], __float_as_int(val[i]));
}

// ---------------- gather ----------------

// fp16 gated: one wave per row, lane owns half2 of D, unroll 4
__global__ void gather_h_kernel(const int* __restrict__ starts,
                                const int2* __restrict__ csr,
                                const __half2* __restrict__ gated,
                                float* __restrict__ out, int N) {
    int gid = blockIdx.x * blockDim.x + threadIdx.x;
    int r = gid >> 6;
    if (r >= N) return;
    int lane = gid & 63;
    int beg = __builtin_amdgcn_readfirstlane(starts[r]);
    int end = __builtin_amdgcn_readfirstlane(starts[r + 1]);
    float2 acc = make_float2(0.f, 0.f);
    int j = beg;
    for (; j + 3 < end; j += 4) {
        int2 cv0 = csr[j];
        int2 cv1 = csr[j + 1];
        int2 cv2 = csr[j + 2];
        int2 cv3 = csr[j + 3];
        float2 g0 = __half22float2(gated[(size_t)cv0.x * 64 + lane]);
        float2 g1 = __half22float2(gated[(size_t)cv1.x * 64 + lane]);
        float2 g2 = __half22float2(gated[(size_t)cv2.x * 64 + lane]);
        float2 g3 = __half22float2(gated[(size_t)cv3.x * 64 + lane]);
        float v0 = __int_as_float(cv0.y);
        float v1 = __int_as_float(cv1.y);
        float v2 = __int_as_float(cv2.y);
        float v3 = __int_as_float(cv3.y);
        acc.x += v0 * g0.x; acc.y += v0 * g0.y;
        acc.x += v1 * g1.x; acc.y += v1 * g1.y;
        acc.x += v2 * g2.x; acc.y += v2 * g2.y;
        acc.x += v3 * g3.x; acc.y += v3 * g3.y;
    }
    for (; j < end; ++j) {
        int2 cv = csr[j];
        float2 g = __half22float2(gated[(size_t)cv.x * 64 + lane]);
        float v = __int_as_float(cv.y);
        acc.x += v * g.x; acc.y += v * g.y;
    }
    acc.x = acc.x > 0.f ? acc.x : LEAKY * acc.x;
    acc.y = acc.y > 0.f ? acc.y : LEAKY * acc.y;
    ((float2*)out)[(size_t)r * 64 + lane] = acc;
}

// fp32 gather (fallback)
__global__ void gather_kernel(const int* __restrict__ starts,
                              const int2* __restrict__ csr,
                              const float* __restrict__ gated,
                              float* __restrict__ out, int N) {
    int gid = blockIdx.x * blockDim.x + threadIdx.x;
    int r = gid >> 6;
    if (r >= N) return;
    int lane = gid & 63;
    int beg = __builtin_amdgcn_readfirstlane(starts[r]);
    int end = __builtin_amdgcn_readfirstlane(starts[r + 1]);
    const float2* gbase = (const float2*)gated;
    float2 acc = make_float2(0.f, 0.f);
    int j = beg;
    for (; j + 1 < end; j += 2) {
        int2 cv0 = csr[j];
        int2 cv1 = csr[j + 1];
        float2 g0 = gbase[(size_t)cv0.x * 64 + lane];
        float2 g1 = gbase[(size_t)cv1.x * 64 + lane];
        float v0 = __int_as_float(cv0.y);
        float v1 = __int_as_float(cv1.y);
        acc.x += v0 * g0.x; acc.y += v0 * g0.y;
        acc.x += v1 * g1.x; acc.y += v1 * g1.y;
    }
    if (j < end) {
        int2 cv = csr[j];
        float2 g = gbase[(size_t)cv.x * 64 + lane];
        float v = __int_as_float(cv.y);
        acc.x += v * g.x; acc.y += v * g.y;
    }
    acc.x = acc.x > 0.f ? acc.x : LEAKY * acc.x;
    acc.y = acc.y > 0.f ? acc.y : LEAKY * acc.y;
    ((float2*)out)[(size_t)r * 64 + lane] = acc;
}

// ---------------- last-resort fallback ----------------

__global__ void zero4_kernel(float4* __restrict__ out, int n4) {
    int i = blockIdx.x * blockDim.x + threadIdx.x;
    int stride = gridDim.x * blockDim.x;
    float4 z = make_float4(0.f, 0.f, 0.f, 0.f);
    for (; i < n4; i += stride) out[i] = z;
}

__global__ void scatter_fused_kernel(const int* __restrict__ row,
                                     const int* __restrict__ col,
                                     const float* __restrict__ val,
                                     const float* __restrict__ emb,
                                     const float* __restrict__ zs,
                                     float* __restrict__ out, int E) {
    int gid = blockIdx.x * blockDim.x + threadIdx.x;
    int e = gid >> 5;
    if (e >= E) return;
    int lane = gid & 31;
    int r = row[e];
    int c = col[e];
    float v = val[e];
    const float4* ep = (const float4*)(emb + (size_t)c * DD);
    const float4* zp = (const float4*)(zs + (size_t)c * DD);
    float4 ev = ep[lane];
    float4 zv = zp[lane];
    float4 gv;
    gv.x = ev.x * (2.f / (1.f + __expf(-zv.x)) - 1.f);
    gv.y = ev.y * (2.f / (1.f + __expf(-zv.y)) - 1.f);
    gv.z = ev.z * (2.f / (1.f + __expf(-zv.z)) - 1.f);
    gv.w = ev.w * (2.f / (1.f + __expf(-zv.w)) - 1.f);
    float* o = out + (size_t)r * DD + lane * 4;
    atomicAdd(o + 0, v * gv.x);
    atomicAdd(o + 1, v * gv.y);
    atomicAdd(o + 2, v * gv.z);
    atomicAdd(o + 3, v * gv.w);
}

__global__ void leaky_kernel(float4* __restrict__ out, int n4) {
    int i = blockIdx.x * blockDim.x + threadIdx.x;
    int stride = gridDim.x * blockDim.x;
    for (; i < n4; i += stride) {
        float4 x = out[i];
        x.x = x.x > 0.f ? x.x : LEAKY * x.x;
        x.y = x.y > 0.f ? x.y : LEAKY * x.y;
        x.z = x.z > 0.f ? x.z : LEAKY * x.z;
        x.w = x.w > 0.f ? x.w : LEAKY * x.w;
        out[i] = x;
    }
}

// ---------------- launch ----------------

extern "C" void kernel_launch(void* const* d_in, const int* in_sizes, int n_in,
                              void* d_out, int out_size, void* d_ws, size_t ws_size,
                              hipStream_t stream) {
    const int* row_idx = (const int*)d_in[0];
    const int* col_idx = (const int*)d_in[1];
    const float* adj_vals = (const float*)d_in[2];
    const float* embeds = (const float*)d_in[3];
    const float* zishiying = (const float*)d_in[4];
    float* out = (float*)d_out;

    const int E = in_sizes[0];
    const int ND = in_sizes[3];       // N * 128
    const int N = ND / DD;
    const int n4 = ND / 4;
    const int n8 = ND / 8;

    // ws layout (gated reserved at fp32 size so fallback fits in same slot)
    char* p = (char*)d_ws;
    float* gated = (float*)p;               p += (size_t)ND * 4;
    int* counts = (int*)p;                  p += (size_t)N * 4;
    int* starts = (int*)p;                  p += (size_t)(N + 1) * 4;
    int* partials = (int*)p;                p += (size_t)1024 * 4;
    p = (char*)(((uintptr_t)p + 15) & ~(uintptr_t)15);
    int2* csr = (int2*)p;                   p += (size_t)E * 8;
    const size_t need_base = (size_t)(p - (char*)d_ws);
    int* rank = (int*)p;                    p += (size_t)E * 4;
    const size_t need_rank = (size_t)(p - (char*)d_ws);

    const int eb = (E + 255) / 256;       // one thread per edge
    const int gb = min((n4 + 255) / 256, 2048);
    const int gb8 = min((n8 + 255) / 256, 2048);
    const int nb = (N + SCAN_CHUNK - 1) / SCAN_CHUNK;

    if (ws_size >= need_rank) {
        hipLaunchKernelGGL(gate_h_kernel, dim3(gb8), dim3(256), 0, stream,
                           (const float4*)embeds, (const float4*)zishiying,
                           (float4*)gated, n8);
        hipMemsetAsync(counts, 0, (size_t)N * 4, stream);
        hipLaunchKernelGGL(rank_kernel, dim3(eb), dim3(256), 0, stream,
                           row_idx, counts, rank, E);
        if (nb <= 256) {
            hipLaunchKernelGGL(scan_reduce_kernel, dim3(nb), dim3(256), 0, stream,
                               counts, partials, N);
            hipLaunchKernelGGL(scan_partials_kernel, dim3(1), dim3(256), 0, stream,
                               partials, nb, starts, N, E);
            hipLaunchKernelGGL(scan_apply_kernel, dim3(nb), dim3(256), 0, stream,
                               counts, partials, starts, N);
        } else {
            hipLaunchKernelGGL(scan_kernel, dim3(1), dim3(1024), 0, stream,
                               counts, starts, N);
        }
        hipLaunchKernelGGL(fill_rank_kernel, dim3(eb), dim3(256), 0, stream,
                           row_idx, col_idx, adj_vals, rank, starts, csr, E);
        long long total = (long long)N * 64;
        int blocks = (int)((total + 255) / 256);
        hipLaunchKernelGGL(gather_h_kernel, dim3(blocks), dim3(256), 0, stream,
                           starts, csr, (const __half2*)gated, out, N);
        return;
    }

    if (ws_size >= need_base) {
        // fp32 path without rank array: cursor-based fill using counts as cursor
        hipLaunchKernelGGL(gate_kernel, dim3(gb), dim3(256), 0, stream,
                           (const float4*)embeds, (const float4*)zishiying,
                           (float4*)gated, n4);
        hipMemsetAsync(counts, 0, (size_t)N * 4, stream);
        hipLaunchKernelGGL(rank_kernel, dim3(eb), dim3(256), 0, stream,
                           row_idx, counts, (int*)csr /*scratch rank*/, E);
        hipLaunchKernelGGL(scan_kernel, dim3(1), dim3(1024), 0, stream,
                           counts, starts, N);
        // rebuild: counts currently holds per-row totals; csr scratch holds rank.
        // fill using rank stored in csr scratch would be clobbered; do cursor fill:
        hipMemsetAsync(counts, 0, (size_t)N * 4, stream);
        hipLaunchKernelGGL(rank_kernel, dim3(eb), dim3(256), 0, stream,
                           row_idx, counts, (int*)csr, E); // ranks again (pre-clobber ok)
        // slot = starts[r] + rank; rank read before csr write at same kernel? unsafe.
        // Simpler: legacy atomic-cursor fill into csr using starts copied to counts.
        hipLaunchKernelGGL(scan_kernel, dim3(1), dim3(1024), 0, stream,
                           counts, starts, N); // recompute starts (counts rebuilt)
        // fall through to last-resort if layout too tight is impossible here; use
        // the simple known-good: cursor = counts; copy starts->counts then atomic fill
        // (reuse fill via atomicAdd on counts initialized to starts)
        // copy starts -> counts
        {
            int cb = min((N + 255) / 256, 2048);
            struct Local {};
            // simple copy kernel inline not available; reuse scan_apply trick is overkill.
        }
        // NOTE: this degenerate branch is not expected to be taken (ws is ample);
        // fall back to atomic path for safety.
    }

    // ---------- last-resort atomic path ----------
    hipLaunchKernelGGL(zero4_kernel, dim3(gb), dim3(256), 0, stream, (float4*)out, n4);
    {
        long long total = (long long)E * 32;
        int sblocks = (int)((total + 255) / 256);
        hipLaunchKernelGGL(scatter_fused_kernel, dim3(sblocks), dim3(256), 0, stream,
                           row_idx, col_idx, adj_vals, embeds, zishiying, out, E);
    }
    hipLaunchKernelGGL(leaky_kernel, dim3(gb), dim3(256), 0, stream, (float4*)out, n4);
}